// Round 9
// baseline (92.269 us; speedup 1.0000x reference)
//
#include <hip/hip_runtime.h>
#include <math.h>

// Problem geometry (fixed by the reference's setup_inputs)
#define NAUX 32
#define NB   64
#define NF   80
#define NT   640
#define PERB (NF * NT)          // 51200 elements per batch
#define NTOT (NB * PERB)        // 3276800 elements per channel
#define RUNB  (PERB / 4)        // elements per wave run (12800, 1/4 batch)
#define STEPB 512               // elements per wave per iter (64 lanes x 8)
#define NITB  (RUNB / STEPB)    // 25 iterations

typedef float f32x4 __attribute__((ext_vector_type(4)));

// x >= 20.0f  <=>  x > predecessor(20.0f):  peak(x) <=> x > max3(l, r, THRM)
#define THRM __uint_as_float(0x419FFFFFu)   // 19.999998...f

// 8-element strict-local-max predicate bits (elems 0-7 -> bits 0-7).
__device__ __forceinline__ unsigned int peak8(
    const f32x4& a, const f32x4& b, float xmL, float xpR)
{
    unsigned int pb = 0;
    pb |= (a[0] > fmaxf(fmaxf(xmL,  a[1]), THRM)) ? 0x01u : 0u;
    pb |= (a[1] > fmaxf(fmaxf(a[0], a[2]), THRM)) ? 0x02u : 0u;
    pb |= (a[2] > fmaxf(fmaxf(a[1], a[3]), THRM)) ? 0x04u : 0u;
    pb |= (a[3] > fmaxf(fmaxf(a[2], b[0]), THRM)) ? 0x08u : 0u;
    pb |= (b[0] > fmaxf(fmaxf(a[3], b[1]), THRM)) ? 0x10u : 0u;
    pb |= (b[1] > fmaxf(fmaxf(b[0], b[2]), THRM)) ? 0x20u : 0u;
    pb |= (b[2] > fmaxf(fmaxf(b[1], b[3]), THRM)) ? 0x40u : 0u;
    pb |= (b[3] > fmaxf(fmaxf(b[2], xpR),  THRM)) ? 0x80u : 0u;
    return pb;
}

// ---------------------------------------------------------------------------
// Single fused kernel: one block per (aux n, batch b). Streams the aux
// channel (nontemporal, HBM-bound) while RECOMPUTING the strain peak mask
// for batch b inline from cache-resident qt_strain (12.5 MB total; XCD-
// grouped block map keeps each XCD's strain working set at 1.6 MB -> L2).
// No workspace, no second kernel, no grid sync. Peak predicate spans the
// FULL flattened channel (batch-crossing neighbors via run-edge loads).
// ---------------------------------------------------------------------------
__global__ __launch_bounds__(256, 8) void fused_stats_kernel(
    const float* __restrict__ qs,
    const float* __restrict__ qa,
    float* __restrict__ out)
{
    // XCD-aware mapping: dispatch round-robins blocks over 8 XCDs, so give
    // XCD k the batches [8k, 8k+8) -> strain working set 1.6 MB/XCD (L2-fits).
    const int p = blockIdx.x;
    const int b = (p & 7) * 8 + ((p >> 3) & 7);
    const int n = p >> 6;

    const int tid  = threadIdx.x;
    const int lane = tid & 63;
    const int w    = tid >> 6;
    const float* __restrict__ pa = qa + (size_t)n * NTOT;

    const int runbase  = b * PERB + w * RUNB;        // wave's contiguous run
    const int lanebase = runbase + lane * 8;

    // Run-edge neighbors for both streams (wave-uniform, 1 line each).
    const float aL = (runbase > 0)           ? pa[runbase - 1]    : INFINITY;
    const float aE = (runbase + RUNB < NTOT) ? pa[runbase + RUNB] : INFINITY;
    const float sL = (runbase > 0)           ? qs[runbase - 1]    : INFINITY;
    const float sE = (runbase + RUNB < NTOT) ? qs[runbase + RUNB] : INFINITY;

    // Prologue: iteration-0 buffers. Aux nontemporal (stream), strain cached.
    f32x4 a0 = __builtin_nontemporal_load(reinterpret_cast<const f32x4*>(pa + lanebase));
    f32x4 a1 = __builtin_nontemporal_load(reinterpret_cast<const f32x4*>(pa + lanebase + 4));
    f32x4 s0v = *reinterpret_cast<const f32x4*>(qs + lanebase);
    f32x4 s1v = *reinterpret_cast<const f32x4*>(qs + lanebase + 4);

    float prevA = aL, prevS = sL;
    unsigned int inter = 0, c1 = 0, c2 = 0;

    for (int i = 0; i < NITB; ++i) {
        const bool last = (i == NITB - 1);
        f32x4 na0 = a0, na1 = a1, ns0 = s0v, ns1 = s1v;
        if (!last) {
            const int nb_ = lanebase + (i + 1) * STEPB;
            na0 = __builtin_nontemporal_load(reinterpret_cast<const f32x4*>(pa + nb_));
            na1 = __builtin_nontemporal_load(reinterpret_cast<const f32x4*>(pa + nb_ + 4));
            ns0 = *reinterpret_cast<const f32x4*>(qs + nb_);
            ns1 = *reinterpret_cast<const f32x4*>(qs + nb_ + 4);
        }
        const float nfA = last ? aE : __shfl(na0[0], 0);
        const float nfS = last ? sE : __shfl(ns0[0], 0);

        const float upA = __shfl_up(a1[3], 1),  dnA = __shfl_down(a0[0], 1);
        const float upS = __shfl_up(s1v[3], 1), dnS = __shfl_down(s0v[0], 1);
        const float xmLa = (lane == 0)  ? prevA : upA;
        const float xpRa = (lane == 63) ? nfA   : dnA;
        const float xmLs = (lane == 0)  ? prevS : upS;
        const float xpRs = (lane == 63) ? nfS   : dnS;

        const unsigned int ps = peak8(s0v, s1v, xmLs, xpRs);
        const unsigned int pa_ = peak8(a0, a1, xmLa, xpRa);

        c1    += __popc(ps);
        c2    += __popc(pa_);
        inter += __popc(ps & pa_);

        prevA = __shfl(a1[3], 63);
        prevS = __shfl(s1v[3], 63);
        a0 = na0; a1 = na1; s0v = ns0; s1v = ns1;
    }

    __shared__ unsigned int r0[256];
    __shared__ unsigned int r1[256];
    __shared__ unsigned int r2[256];
    r0[tid] = inter; r1[tid] = c1; r2[tid] = c2;
    __syncthreads();
    for (int off = 128; off > 0; off >>= 1) {
        if (tid < off) {
            r0[tid] += r0[tid + off];
            r1[tid] += r1[tid + off];
            r2[tid] += r2[tid + off];
        }
        __syncthreads();
    }

    if (tid == 0) {
        const float fi = (float)r0[0];
        const float f1 = (float)r1[0];
        const float f2 = (float)r2[0];
        const float un = f1 + f2 - fi;
        float jac, ratio;
        if (fi == 0.0f && un == 0.0f) {        // zero_union -> 1.0, 1.0
            jac = 1.0f; ratio = 1.0f;
        } else {
            jac   = fi / un;                              // un > 0 here
            ratio = (f1 > 0.0f) ? (fi / f1) : 0.0f;       // 0/0 -> nan_to_num -> 0
        }
        out[n * NB + b]             = jac;     // iou.reshape(-1)
        out[NAUX * NB + n * NB + b] = ratio;   // corr.reshape(-1)
    }
}

extern "C" void kernel_launch(void* const* d_in, const int* in_sizes, int n_in,
                              void* d_out, int out_size, void* d_ws, size_t ws_size,
                              hipStream_t stream) {
    const float* qs = (const float*)d_in[0];   // [64, 80, 640]
    const float* qa = (const float*)d_in[1];   // [32, 64, 80, 640]
    float* outp = (float*)d_out;               // [4096] = iou ++ corr

    fused_stats_kernel<<<NAUX * NB, 256, 0, stream>>>(qs, qa, outp);
}

// Round 10
// 86.523 us; speedup vs baseline: 1.0664x; 1.0664x over previous
//
#include <hip/hip_runtime.h>
#include <math.h>

// Problem geometry (fixed by the reference's setup_inputs)
#define NAUX 32
#define NB   64
#define NF   80
#define NT   640
#define PERB (NF * NT)          // 51200 elements per batch
#define NTOT (NB * PERB)        // 3276800 elements per channel
#define NGRP (NTOT / 4)         // 819200 4-element groups -> mask bytes
#define ASEG 10                 // A: blocks per batch (5120 elems each)
#define AUNR 5                  // A: k-chunks per wave-run
#define WRUNA (AUNR * 256)      // A: elements per wave run (1280)
#define RUNB  (PERB / 4)        // B: elements per wave run (12800, 1/4 batch)
#define STEPB 512               // B: elements per wave per iter (64 lanes x 8)
#define NITB  (RUNB / STEPB)    // 25 iterations
#define MB_BATCH (PERB / 4)     // mask bytes per batch (12800)

typedef float f32x4 __attribute__((ext_vector_type(4)));

// x >= 20.0f  <=>  x > predecessor(20.0f):  peak(x) <=> x > max3(l, r, THRM)
#define THRM __uint_as_float(0x419FFFFFu)   // 19.999998...f

// ---------------------------------------------------------------------------
// Strict-local-max predicate over the FULL flattened [B,F,T] channel (peaks
// cross batch boundaries; only channel-flat 0 and NTOT-1 excluded).
// clip(min=0) is a no-op given the >=20 requirement.
// Mask layout: byte g holds the 4-bit predicate nibble for elements 4g..4g+3.
// ---------------------------------------------------------------------------

// Kernel A: 640 blocks; block covers 5120 elements = 4 wave-runs of 1280.
__global__ __launch_bounds__(256) void strain_mask_kernel(
    const float* __restrict__ qs,
    unsigned char* __restrict__ maskb,
    unsigned int* __restrict__ c1part)
{
    const int tid  = threadIdx.x;
    const int lane = tid & 63;
    const int w    = tid >> 6;
    const int base = blockIdx.x * (4 * WRUNA) + w * WRUNA + lane * 4;

    f32x4 v[AUNR];
    #pragma unroll
    for (int k = 0; k < AUNR; ++k)
        v[k] = *reinterpret_cast<const f32x4*>(qs + base + k * 256);

    float xmE = INFINITY, xpE = INFINITY;
    if (lane == 0)  { const int g = base - 1;                    if (g >= 0)   xmE = qs[g]; }
    if (lane == 63) { const int g = base + (AUNR - 1) * 256 + 4; if (g < NTOT) xpE = qs[g]; }

    unsigned int cnt = 0;
    #pragma unroll
    for (int k = 0; k < AUNR; ++k) {
        const float prevw = __shfl(v[k > 0 ? k - 1 : 0][3], 63);
        const float nextx = __shfl(v[k < AUNR - 1 ? k + 1 : AUNR - 1][0], 0);
        float xm = __shfl_up(v[k][3], 1);
        float xp = __shfl_down(v[k][0], 1);
        xm = (lane == 0)  ? ((k > 0)        ? prevw : xmE) : xm;
        xp = (lane == 63) ? ((k < AUNR - 1) ? nextx : xpE) : xp;

        unsigned int pb = 0;
        pb |= (v[k][0] > fmaxf(fmaxf(xm,      v[k][1]), THRM)) ? 1u : 0u;
        pb |= (v[k][1] > fmaxf(fmaxf(v[k][0], v[k][2]), THRM)) ? 2u : 0u;
        pb |= (v[k][2] > fmaxf(fmaxf(v[k][1], v[k][3]), THRM)) ? 4u : 0u;
        pb |= (v[k][3] > fmaxf(fmaxf(v[k][2], xp),      THRM)) ? 8u : 0u;

        maskb[(base + k * 256) >> 2] = (unsigned char)pb;   // coalesced bytes
        cnt += __popc(pb);
    }

    __shared__ unsigned int s[256];
    s[tid] = cnt;
    __syncthreads();
    for (int off = 128; off > 0; off >>= 1) {
        if (tid < off) s[tid] += s[tid + off];
        __syncthreads();
    }
    if (tid == 0) c1part[blockIdx.x] = s[0];
}

// Kernel B: one block per (aux n, batch b). Batch mask (12.8 KB) staged to
// LDS once per block (coalesced uint4 burst, L2-hits); steady-state loop
// issues ONLY the two streaming aux dwordx4 on the VMEM path — mask comes
// from ds_read_u16 (2B/lane = 2-way bank alias, free). Zero edge loads and
// zero barriers in the loop; register-local neighbors; 2-deep pipeline.
__global__ __launch_bounds__(256) void aux_stats_kernel(
    const float* __restrict__ qa,
    const unsigned char* __restrict__ maskb,
    const unsigned int* __restrict__ c1part,
    float* __restrict__ out)
{
    const int n    = blockIdx.x >> 6;   // / NB
    const int b    = blockIdx.x & 63;   // % NB
    const int tid  = threadIdx.x;
    const int lane = tid & 63;
    const int w    = tid >> 6;
    const float* __restrict__ pn = qa + (size_t)n * NTOT;

    __shared__ unsigned short smask[MB_BATCH / 2];   // 6400 ushorts = 12.8 KB

    // Stage batch b's mask bytes -> LDS (800 x uint4, coalesced, L2-hit).
    {
        const uint4* msrc = reinterpret_cast<const uint4*>(maskb + (size_t)b * MB_BATCH);
        uint4* mdst = reinterpret_cast<uint4*>(smask);
        for (int idx = tid; idx < MB_BATCH / 16; idx += 256) mdst[idx] = msrc[idx];
    }
    __syncthreads();

    const int runbase  = b * PERB + w * RUNB;        // wave's contiguous run
    const int lanebase = runbase + lane * 8;

    // Run-edge neighbors: loaded ONCE (wave-uniform addresses, 1 line each).
    const float runL   = (runbase > 0)           ? pn[runbase - 1]    : INFINITY;
    const float runEnd = (runbase + RUNB < NTOT) ? pn[runbase + RUNB] : INFINITY;

    // Prologue: iteration-0 buffers.
    f32x4 c0 = *reinterpret_cast<const f32x4*>(pn + lanebase);
    f32x4 c1 = *reinterpret_cast<const f32x4*>(pn + lanebase + 4);

    float prevLast = runL;                 // left neighbor of the run so far
    unsigned int inter = 0, c2 = 0;
    const int mbase = w * (NITB * 64) + lane;        // ushort idx: w*1600+lane

    for (int i = 0; i < NITB; ++i) {
        const bool last = (i == NITB - 1);
        f32x4 n0 = c0, n1 = c1;
        if (!last) {
            const int nb_ = lanebase + (i + 1) * STEPB;
            n0 = *reinterpret_cast<const f32x4*>(pn + nb_);
            n1 = *reinterpret_cast<const f32x4*>(pn + nb_ + 4);
        }
        const unsigned int m = smask[mbase + i * 64];   // ds_read_u16
        const float nextFirst = last ? runEnd : __shfl(n0[0], 0);

        const float sUp = __shfl_up(c1[3], 1);
        const float sDn = __shfl_down(c0[0], 1);
        const float xmL = (lane == 0)  ? prevLast  : sUp;  // left  of elem 0
        const float xpR = (lane == 63) ? nextFirst : sDn;  // right of elem 7

        // peak(x) <=> x > max3(left, right, THRM); elems 0-3 -> bits 0-3,
        // elems 4-7 -> bits 8-11 (matches mask-ushort byte layout).
        unsigned int pb = 0;
        pb |= (c0[0] > fmaxf(fmaxf(xmL,   c0[1]), THRM)) ? 0x001u : 0u;
        pb |= (c0[1] > fmaxf(fmaxf(c0[0], c0[2]), THRM)) ? 0x002u : 0u;
        pb |= (c0[2] > fmaxf(fmaxf(c0[1], c0[3]), THRM)) ? 0x004u : 0u;
        pb |= (c0[3] > fmaxf(fmaxf(c0[2], c1[0]), THRM)) ? 0x008u : 0u;
        pb |= (c1[0] > fmaxf(fmaxf(c0[3], c1[1]), THRM)) ? 0x100u : 0u;
        pb |= (c1[1] > fmaxf(fmaxf(c1[0], c1[2]), THRM)) ? 0x200u : 0u;
        pb |= (c1[2] > fmaxf(fmaxf(c1[1], c1[3]), THRM)) ? 0x400u : 0u;
        pb |= (c1[3] > fmaxf(fmaxf(c1[2], xpR),   THRM)) ? 0x800u : 0u;

        c2    += __popc(pb);
        inter += __popc(pb & m);

        prevLast = __shfl(c1[3], 63);      // carry run-left for next iter
        c0 = n0; c1 = n1;
    }

    __shared__ unsigned int si[256];
    __shared__ unsigned int sc[256];
    si[tid] = inter; sc[tid] = c2;
    __syncthreads();
    for (int off = 128; off > 0; off >>= 1) {
        if (tid < off) { si[tid] += si[tid + off]; sc[tid] += sc[tid + off]; }
        __syncthreads();
    }

    if (tid == 0) {
        unsigned int c1s = 0;
        #pragma unroll
        for (int s2 = 0; s2 < ASEG; ++s2) c1s += c1part[b * ASEG + s2];
        const float fi = (float)si[0];
        const float f1 = (float)c1s;
        const float f2 = (float)sc[0];
        const float un = f1 + f2 - fi;
        float jac, ratio;
        if (fi == 0.0f && un == 0.0f) {        // zero_union -> 1.0, 1.0
            jac = 1.0f; ratio = 1.0f;
        } else {
            jac   = fi / un;                              // un > 0 here
            ratio = (f1 > 0.0f) ? (fi / f1) : 0.0f;       // 0/0 -> nan_to_num -> 0
        }
        out[n * NB + b]             = jac;     // iou.reshape(-1)
        out[NAUX * NB + n * NB + b] = ratio;   // corr.reshape(-1)
    }
}

extern "C" void kernel_launch(void* const* d_in, const int* in_sizes, int n_in,
                              void* d_out, int out_size, void* d_ws, size_t ws_size,
                              hipStream_t stream) {
    const float* qs = (const float*)d_in[0];   // [64, 80, 640]
    const float* qa = (const float*)d_in[1];   // [32, 64, 80, 640]
    float* outp = (float*)d_out;               // [4096] = iou ++ corr

    unsigned char* maskb = (unsigned char*)d_ws;                 // 819200 bytes
    unsigned int*  c1p   = (unsigned int*)(maskb + NGRP);        // 640 words

    strain_mask_kernel<<<NB * ASEG, 256, 0, stream>>>(qs, maskb, c1p);
    aux_stats_kernel<<<NAUX * NB, 256, 0, stream>>>(qa, maskb, c1p, outp);
}

// Round 11
// 84.470 us; speedup vs baseline: 1.0923x; 1.0243x over previous
//
#include <hip/hip_runtime.h>
#include <math.h>

// Problem geometry (fixed by the reference's setup_inputs)
#define NAUX 32
#define NB   64
#define NF   80
#define NT   640
#define PERB (NF * NT)          // 51200 elements per batch
#define NTOT (NB * PERB)        // 3276800 elements per channel
#define NGRP (NTOT / 4)         // 819200 4-element groups -> mask bytes
#define ASEG 10                 // A: blocks per batch (5120 elems each)
#define AUNR 5                  // A: k-chunks per wave-run
#define WRUNA (AUNR * 256)      // A: elements per wave run (1280)
#define RUNB  (PERB / 4)        // B: elements per wave run (12800, 1/4 batch)
#define STEPB 512               // B: elements per wave per iter (64 lanes x 8)
#define NITB  (RUNB / STEPB)    // 25 iterations

typedef float f32x4 __attribute__((ext_vector_type(4)));

// x >= 20.0f  <=>  x > predecessor(20.0f):  peak(x) <=> x > max3(l, r, THRM)
#define THRM __uint_as_float(0x419FFFFFu)   // 19.999998...f

// ---------------------------------------------------------------------------
// Strict-local-max predicate over the FULL flattened [B,F,T] channel (peaks
// cross batch boundaries; only channel-flat 0 and NTOT-1 excluded).
// clip(min=0) is a no-op given the >=20 requirement.
// Mask layout: byte g holds the 4-bit predicate nibble for elements 4g..4g+3.
// ---------------------------------------------------------------------------

// Kernel A: 640 blocks; block covers 5120 elements = 4 wave-runs of 1280.
__global__ __launch_bounds__(256) void strain_mask_kernel(
    const float* __restrict__ qs,
    unsigned char* __restrict__ maskb,
    unsigned int* __restrict__ c1part)
{
    const int tid  = threadIdx.x;
    const int lane = tid & 63;
    const int w    = tid >> 6;
    const int base = blockIdx.x * (4 * WRUNA) + w * WRUNA + lane * 4;

    f32x4 v[AUNR];
    #pragma unroll
    for (int k = 0; k < AUNR; ++k)
        v[k] = *reinterpret_cast<const f32x4*>(qs + base + k * 256);

    float xmE = INFINITY, xpE = INFINITY;
    if (lane == 0)  { const int g = base - 1;                    if (g >= 0)   xmE = qs[g]; }
    if (lane == 63) { const int g = base + (AUNR - 1) * 256 + 4; if (g < NTOT) xpE = qs[g]; }

    unsigned int cnt = 0;
    #pragma unroll
    for (int k = 0; k < AUNR; ++k) {
        const float prevw = __shfl(v[k > 0 ? k - 1 : 0][3], 63);
        const float nextx = __shfl(v[k < AUNR - 1 ? k + 1 : AUNR - 1][0], 0);
        float xm = __shfl_up(v[k][3], 1);
        float xp = __shfl_down(v[k][0], 1);
        xm = (lane == 0)  ? ((k > 0)        ? prevw : xmE) : xm;
        xp = (lane == 63) ? ((k < AUNR - 1) ? nextx : xpE) : xp;

        unsigned int pb = 0;
        pb |= (v[k][0] > fmaxf(fmaxf(xm,      v[k][1]), THRM)) ? 1u : 0u;
        pb |= (v[k][1] > fmaxf(fmaxf(v[k][0], v[k][2]), THRM)) ? 2u : 0u;
        pb |= (v[k][2] > fmaxf(fmaxf(v[k][1], v[k][3]), THRM)) ? 4u : 0u;
        pb |= (v[k][3] > fmaxf(fmaxf(v[k][2], xp),      THRM)) ? 8u : 0u;

        maskb[(base + k * 256) >> 2] = (unsigned char)pb;   // coalesced bytes
        cnt += __popc(pb);
    }

    __shared__ unsigned int s[256];
    s[tid] = cnt;
    __syncthreads();
    for (int off = 128; off > 0; off >>= 1) {
        if (tid < off) s[tid] += s[tid + off];
        __syncthreads();
    }
    if (tid == 0) c1part[blockIdx.x] = s[0];
}

// Kernel B: one block per (aux n, batch b). Wave owns a contiguous 12800-elem
// run; lane owns 8 contiguous elems per 512-elem step (register-local
// neighbors, 2 shuffles, carried boundary reg). ushort mask load per iter
// (L2-hit). 2-deep pipeline, zero edge loads / barriers in the loop.
// __launch_bounds__(256,8): cap VGPR<=64 so all 2048 blocks are co-resident
// (8 blocks/CU) — removes any serialization tail and maximizes in-flight loads.
__global__ __launch_bounds__(256, 8) void aux_stats_kernel(
    const float* __restrict__ qa,
    const unsigned char* __restrict__ maskb,
    const unsigned int* __restrict__ c1part,
    float* __restrict__ out)
{
    const int n    = blockIdx.x >> 6;   // / NB
    const int b    = blockIdx.x & 63;   // % NB
    const int tid  = threadIdx.x;
    const int lane = tid & 63;
    const int w    = tid >> 6;
    const float* __restrict__ pn = qa + (size_t)n * NTOT;

    const int runbase  = b * PERB + w * RUNB;        // wave's contiguous run
    const int lanebase = runbase + lane * 8;

    // Run-edge neighbors: loaded ONCE (wave-uniform addresses, 1 line each).
    const float runL   = (runbase > 0)           ? pn[runbase - 1]    : INFINITY;
    const float runEnd = (runbase + RUNB < NTOT) ? pn[runbase + RUNB] : INFINITY;

    // Prologue: iteration-0 buffers.
    f32x4 c0 = *reinterpret_cast<const f32x4*>(pn + lanebase);
    f32x4 c1 = *reinterpret_cast<const f32x4*>(pn + lanebase + 4);
    unsigned int m = *reinterpret_cast<const unsigned short*>(maskb + (lanebase >> 2));

    float prevLast = runL;                 // left neighbor of the run so far
    unsigned int inter = 0, c2 = 0;

    for (int i = 0; i < NITB; ++i) {
        const bool last = (i == NITB - 1);
        f32x4 n0 = c0, n1 = c1; unsigned int nm = m;
        if (!last) {
            const int nb_ = lanebase + (i + 1) * STEPB;
            n0 = *reinterpret_cast<const f32x4*>(pn + nb_);
            n1 = *reinterpret_cast<const f32x4*>(pn + nb_ + 4);
            nm = *reinterpret_cast<const unsigned short*>(maskb + (nb_ >> 2));
        }
        const float nextFirst = last ? runEnd : __shfl(n0[0], 0);

        const float sUp = __shfl_up(c1[3], 1);
        const float sDn = __shfl_down(c0[0], 1);
        const float xmL = (lane == 0)  ? prevLast  : sUp;  // left  of elem 0
        const float xpR = (lane == 63) ? nextFirst : sDn;  // right of elem 7

        // peak(x) <=> x > max3(left, right, THRM); elems 0-3 -> bits 0-3,
        // elems 4-7 -> bits 8-11 (matches mask-ushort byte layout).
        unsigned int pb = 0;
        pb |= (c0[0] > fmaxf(fmaxf(xmL,   c0[1]), THRM)) ? 0x001u : 0u;
        pb |= (c0[1] > fmaxf(fmaxf(c0[0], c0[2]), THRM)) ? 0x002u : 0u;
        pb |= (c0[2] > fmaxf(fmaxf(c0[1], c0[3]), THRM)) ? 0x004u : 0u;
        pb |= (c0[3] > fmaxf(fmaxf(c0[2], c1[0]), THRM)) ? 0x008u : 0u;
        pb |= (c1[0] > fmaxf(fmaxf(c0[3], c1[1]), THRM)) ? 0x100u : 0u;
        pb |= (c1[1] > fmaxf(fmaxf(c1[0], c1[2]), THRM)) ? 0x200u : 0u;
        pb |= (c1[2] > fmaxf(fmaxf(c1[1], c1[3]), THRM)) ? 0x400u : 0u;
        pb |= (c1[3] > fmaxf(fmaxf(c1[2], xpR),   THRM)) ? 0x800u : 0u;

        c2    += __popc(pb);
        inter += __popc(pb & m);

        prevLast = __shfl(c1[3], 63);      // carry run-left for next iter
        c0 = n0; c1 = n1; m = nm;
    }

    __shared__ unsigned int si[256];
    __shared__ unsigned int sc[256];
    si[tid] = inter; sc[tid] = c2;
    __syncthreads();
    for (int off = 128; off > 0; off >>= 1) {
        if (tid < off) { si[tid] += si[tid + off]; sc[tid] += sc[tid + off]; }
        __syncthreads();
    }

    if (tid == 0) {
        unsigned int c1s = 0;
        #pragma unroll
        for (int s2 = 0; s2 < ASEG; ++s2) c1s += c1part[b * ASEG + s2];
        const float fi = (float)si[0];
        const float f1 = (float)c1s;
        const float f2 = (float)sc[0];
        const float un = f1 + f2 - fi;
        float jac, ratio;
        if (fi == 0.0f && un == 0.0f) {        // zero_union -> 1.0, 1.0
            jac = 1.0f; ratio = 1.0f;
        } else {
            jac   = fi / un;                              // un > 0 here
            ratio = (f1 > 0.0f) ? (fi / f1) : 0.0f;       // 0/0 -> nan_to_num -> 0
        }
        out[n * NB + b]             = jac;     // iou.reshape(-1)
        out[NAUX * NB + n * NB + b] = ratio;   // corr.reshape(-1)
    }
}

extern "C" void kernel_launch(void* const* d_in, const int* in_sizes, int n_in,
                              void* d_out, int out_size, void* d_ws, size_t ws_size,
                              hipStream_t stream) {
    const float* qs = (const float*)d_in[0];   // [64, 80, 640]
    const float* qa = (const float*)d_in[1];   // [32, 64, 80, 640]
    float* outp = (float*)d_out;               // [4096] = iou ++ corr

    unsigned char* maskb = (unsigned char*)d_ws;                 // 819200 bytes
    unsigned int*  c1p   = (unsigned int*)(maskb + NGRP);        // 640 words

    strain_mask_kernel<<<NB * ASEG, 256, 0, stream>>>(qs, maskb, c1p);
    aux_stats_kernel<<<NAUX * NB, 256, 0, stream>>>(qa, maskb, c1p, outp);
}

// Round 12
// 83.244 us; speedup vs baseline: 1.1084x; 1.0147x over previous
//
#include <hip/hip_runtime.h>
#include <math.h>

// Problem geometry (fixed by the reference's setup_inputs)
#define NAUX 32
#define NB   64
#define NF   80
#define NT   640
#define PERB (NF * NT)          // 51200 elements per batch
#define NTOT (NB * PERB)        // 3276800 elements per channel
#define NGRP (NTOT / 4)         // 819200 4-element groups -> mask bytes
#define THR  20.0f
#define UNR  5                  // k-chunks per wave-run (1280 elems = 5 x 256)
#define WRUN (UNR * 256)        // elements per wave run
#define ASEG 10                 // A: blocks per batch (5120 elems each)

// ---------------------------------------------------------------------------
// CHAMPION (R5, 82.7 us). Strict-local-max predicate over the FULL flattened
// [B,F,T] channel (peaks cross batch boundaries; only channel-flat 0 and
// NTOT-1 excluded). clip(min=0) is a no-op given the >=20 requirement.
// Mask layout: byte g holds the 4-bit predicate nibble for elements 4g..4g+3.
//
// Wave-private runs: each wave covers 1280 contiguous elements (5 float4
// chunks, lane-contiguous per chunk). ALL neighbor exchange is intra-wave
// (shuffles + k+-1 broadcasts) except the run's two boundary elements,
// loaded once per run WITH the main burst -> one counted vmcnt drain per
// outer iter, no per-k vmcnt(0) poison, no barriers in the hot loop.
//
// Roofline status: B sustains ~5.2-5.4 TB/s pure read (82% of the 6.3 TB/s
// copy ceiling); 6 structural variants (R7/R9/R10/R11 + fusions) all land
// 83+-2 us -> practical HBM read ceiling for this pattern.
// ---------------------------------------------------------------------------

// Kernel A: 640 blocks; block covers 5120 elements = 4 wave-runs.
__global__ __launch_bounds__(256) void strain_mask_kernel(
    const float* __restrict__ qs,
    unsigned char* __restrict__ maskb,
    unsigned int* __restrict__ c1part)
{
    const int tid  = threadIdx.x;
    const int lane = tid & 63;
    const int w    = tid >> 6;
    const int base = blockIdx.x * (4 * WRUN) + w * WRUN + lane * 4;

    float4 v[UNR];
    #pragma unroll
    for (int k = 0; k < UNR; ++k)
        v[k] = *reinterpret_cast<const float4*>(qs + base + k * 256);

    float xmE = INFINITY, xpE = INFINITY;
    if (lane == 0)  { const int g = base - 1;                  if (g >= 0)   xmE = qs[g]; }
    if (lane == 63) { const int g = base + (UNR - 1) * 256 + 4; if (g < NTOT) xpE = qs[g]; }

    unsigned int cnt = 0;
    #pragma unroll
    for (int k = 0; k < UNR; ++k) {
        const float prevw = __shfl(v[k > 0 ? k - 1 : 0].w, 63);       // full-wave bcast
        const float nextx = __shfl(v[k < UNR - 1 ? k + 1 : UNR - 1].x, 0);
        float xm = __shfl_up(v[k].w, 1);
        float xp = __shfl_down(v[k].x, 1);
        xm = (lane == 0)  ? ((k > 0)       ? prevw : xmE) : xm;
        xp = (lane == 63) ? ((k < UNR - 1) ? nextx : xpE) : xp;

        unsigned int pb = 0;
        pb |= ((v[k].x >= THR) && (v[k].x > xm)     && (v[k].x > v[k].y)) ? 1u : 0u;
        pb |= ((v[k].y >= THR) && (v[k].y > v[k].x) && (v[k].y > v[k].z)) ? 2u : 0u;
        pb |= ((v[k].z >= THR) && (v[k].z > v[k].y) && (v[k].z > v[k].w)) ? 4u : 0u;
        pb |= ((v[k].w >= THR) && (v[k].w > v[k].z) && (v[k].w > xp))     ? 8u : 0u;

        maskb[(base + k * 256) >> 2] = (unsigned char)pb;   // coalesced bytes
        cnt += __popc(pb);
    }

    __shared__ unsigned int s[256];
    s[tid] = cnt;
    __syncthreads();
    for (int off = 128; off > 0; off >>= 1) {
        if (tid < off) s[tid] += s[tid + off];
        __syncthreads();
    }
    if (tid == 0) c1part[blockIdx.x] = s[0];
}

// Kernel B: one block per (aux channel n, batch b); 10 outer iters, each
// wave sweeping a private 1280-element run. No barriers in the loop.
__global__ __launch_bounds__(256) void aux_stats_kernel(
    const float* __restrict__ qa,
    const unsigned char* __restrict__ maskb,
    const unsigned int* __restrict__ c1part,
    float* __restrict__ out)
{
    const int n    = blockIdx.x >> 6;   // / NB
    const int b    = blockIdx.x & 63;   // % NB
    const int tid  = threadIdx.x;
    const int lane = tid & 63;
    const int w    = tid >> 6;
    const float* __restrict__ pn = qa + (size_t)n * NTOT;

    unsigned int inter = 0, c2 = 0;
    const int wbase0 = b * PERB + w * WRUN + lane * 4;

    for (int ot = 0; ot < PERB / (4 * WRUN); ++ot) {        // 10 outer iters
        const int base = wbase0 + ot * (4 * WRUN);

        float4       v[UNR];
        unsigned int sm[UNR];
        #pragma unroll
        for (int k = 0; k < UNR; ++k)
            v[k] = *reinterpret_cast<const float4*>(pn + base + k * 256);

        float xmE = INFINITY, xpE = INFINITY;
        if (lane == 0)  { const int g = base - 1;                   if (g >= 0)   xmE = pn[g]; }
        if (lane == 63) { const int g = base + (UNR - 1) * 256 + 4; if (g < NTOT) xpE = pn[g]; }

        #pragma unroll
        for (int k = 0; k < UNR; ++k)
            sm[k] = maskb[(base + k * 256) >> 2];

        #pragma unroll
        for (int k = 0; k < UNR; ++k) {
            const float prevw = __shfl(v[k > 0 ? k - 1 : 0].w, 63);
            const float nextx = __shfl(v[k < UNR - 1 ? k + 1 : UNR - 1].x, 0);
            float xm = __shfl_up(v[k].w, 1);
            float xp = __shfl_down(v[k].x, 1);
            xm = (lane == 0)  ? ((k > 0)       ? prevw : xmE) : xm;
            xp = (lane == 63) ? ((k < UNR - 1) ? nextx : xpE) : xp;

            unsigned int pb = 0;
            pb |= ((v[k].x >= THR) && (v[k].x > xm)     && (v[k].x > v[k].y)) ? 1u : 0u;
            pb |= ((v[k].y >= THR) && (v[k].y > v[k].x) && (v[k].y > v[k].z)) ? 2u : 0u;
            pb |= ((v[k].z >= THR) && (v[k].z > v[k].y) && (v[k].z > v[k].w)) ? 4u : 0u;
            pb |= ((v[k].w >= THR) && (v[k].w > v[k].z) && (v[k].w > xp))     ? 8u : 0u;

            c2    += __popc(pb);
            inter += __popc(pb & sm[k]);
        }
    }

    __shared__ unsigned int si[256];
    __shared__ unsigned int sc[256];
    si[tid] = inter; sc[tid] = c2;
    __syncthreads();
    for (int off = 128; off > 0; off >>= 1) {
        if (tid < off) { si[tid] += si[tid + off]; sc[tid] += sc[tid + off]; }
        __syncthreads();
    }

    if (tid == 0) {
        unsigned int c1 = 0;
        #pragma unroll
        for (int s2 = 0; s2 < ASEG; ++s2) c1 += c1part[b * ASEG + s2];
        const float fi = (float)si[0];
        const float f1 = (float)c1;
        const float f2 = (float)sc[0];
        const float un = f1 + f2 - fi;
        float jac, ratio;
        if (fi == 0.0f && un == 0.0f) {        // zero_union -> 1.0, 1.0
            jac = 1.0f; ratio = 1.0f;
        } else {
            jac   = fi / un;                              // un > 0 here
            ratio = (f1 > 0.0f) ? (fi / f1) : 0.0f;       // 0/0 -> nan_to_num -> 0
        }
        out[n * NB + b]             = jac;     // iou.reshape(-1)
        out[NAUX * NB + n * NB + b] = ratio;   // corr.reshape(-1)
    }
}

extern "C" void kernel_launch(void* const* d_in, const int* in_sizes, int n_in,
                              void* d_out, int out_size, void* d_ws, size_t ws_size,
                              hipStream_t stream) {
    const float* qs = (const float*)d_in[0];   // [64, 80, 640]
    const float* qa = (const float*)d_in[1];   // [32, 64, 80, 640]
    float* out = (float*)d_out;                // [4096] = iou ++ corr

    unsigned char* maskb = (unsigned char*)d_ws;                 // 819200 bytes
    unsigned int*  c1p   = (unsigned int*)(maskb + NGRP);        // 640 words

    strain_mask_kernel<<<NB * ASEG, 256, 0, stream>>>(qs, maskb, c1p);
    aux_stats_kernel<<<NAUX * NB, 256, 0, stream>>>(qa, maskb, c1p, out);
}